// Round 14
// baseline (534.644 us; speedup 1.0000x reference)
//
#include <hip/hip_runtime.h>
#include <stdint.h>

// ---------------------------------------------------------------------------
// XlaQuantizedLinear: out[M,N] = (x[M,K] @ w[N,K]^T) * scaler[N]
// Round 14: i8 GEMM, tile 128x128, 2-WAVE blocks (128 thr), 4 blocks/CU.
// Rationale: r11-r13 fixed at ~47% MfmaUtil with 66us blocks; 5.375-fill grid
// tail costs ~25-40us. Quarter-size blocks cut tail granularity 4x; per-wave
// program is BYTE-IDENTICAL to r12 (128x64 out, acc[8][4], 64 MFMA +
// 24 ds_read_b128 per K-tile of 128); only addresses/staging counts change.
//
// LDS: 5-region ring x 8KB (64 rows x 128B). Slots/tile: A0@rb,B0@rb+1,
// B1@rb+2,A1@rb+3 (advance 4 mod 5). A0=tile rows 0-63, A1=64-127;
// B0=cols 0-63 (wave0's), B1=cols 64-127 (wave1's).
// Stages: 4 gl_lds/wave/region (region 8KB / 2 waves / 1KB-per-instr).
//  phase | VMW | MMAQ         | reads (after MMAQ)      | stage (t+1)
//  phi1  |  4  | (1,1)[t-1]   | A0->a (8), B_wc lo->b0  | A0 -> rN
//  phi2  |  -  | (0,0)        | B_wc hi->b1 (4)         | B0 -> rA0
//  phi3  |  8  | (0,1)        | A1->a (8)               | B1 -> rB0
//  phi4  |  -  | (1,0)        | --                      | A1 -> rB1
// vmcnt (4 loads/phase/wave): enter phi1: 16 outstanding -> VMW(4) retires
//  A0,B0,B1(t) [read phi1/phi2]. phi3: 12 -> VMW(8) retires A1(t). Leads
//  2-4 phases (~same cycles as r11: phase = 2 waves/SIMD x 16 MFMA).
// WAR (ring-5): B0(t+1)@phi2 over A0(t) read phi1 (gap1+barrier+~900cy
//  gl_lds landing margin — r8/r11 proven); B1(t+1)@phi3 over B0(t) read
//  phi2 (gap1, same); A1(t+1)@phi4 over B1(t) read phi2 (gap2);
//  A0(t+2)@phi1(t+1) over A1(t) read phi3 (gap2). All proven patterns.
// Reg liveness identical to r12 (a refilled after its MMAQ; b0/b1 ping).
// ---------------------------------------------------------------------------

typedef __attribute__((ext_vector_type(4))) int i32x4;      // i8 frag & acc
typedef __attribute__((ext_vector_type(4))) short short4v;
typedef __attribute__((ext_vector_type(4))) float f32x4;

#define NXCD 8
#define RSZ 8192
#define RING 40960

__device__ __forceinline__ short bf16_bits(float f) {
  uint32_t u = __builtin_bit_cast(uint32_t, f);
  uint32_t r = (u + 0x7FFFu + ((u >> 16) & 1u)) >> 16;
  return (short)r;
}

__device__ __forceinline__ void gl_lds16(const void* g, void* l) {
  __builtin_amdgcn_global_load_lds(
      (const __attribute__((address_space(1))) void*)g,
      (__attribute__((address_space(3))) void*)l, 16, 0, 0);
}

__global__ __launch_bounds__(128, 2) void gemm128i8(
    const char* __restrict__ A, const char* __restrict__ B,
    const float* __restrict__ rs, const float* __restrict__ scaler,
    float* __restrict__ C, int M, int N, int K) {
  __shared__ alignas(16) char sm[RING];  // 40 KB -> 4 blocks/CU

  const int tid = threadIdx.x;
  const int l = tid & 63;
  const int w = tid >> 6;          // 0..1; wc = w
  const int ln15 = l & 15;

  // bijective XCD-aware swizzle (m204)
  const int nwg = gridDim.x;
  const int ntn = N >> 7;          // 128-wide tiles along N
  int bid = blockIdx.x;
  int q = nwg / NXCD, rr = nwg % NXCD;
  int xcd = bid % NXCD, idx = bid / NXCD;
  int swz = (xcd < rr ? xcd * (q + 1) : rr * (q + 1) + (xcd - rr) * q) + idx;
  const int m0 = (swz / ntn) << 7, n0 = (swz % ntn) << 7;

  const size_t ldkb = (size_t)K;   // bytes per row (i8)

  // staging per-thread bases (source pre-swizzled: rule 21)
  const int srow8 = l >> 3;                       // 0..7
  const int sswz = ((l & 7) ^ srow8) << 4;
  const char* Ag = A + (size_t)(m0 + w * 8 + srow8) * ldkb + sswz;
  const char* Bg = B + (size_t)(n0 + w * 8 + srow8) * ldkb + sswz;

  // read-side swizzled k offsets (row&7 == l&7 for all frag reads)
  const int swzc = (l & 7) << 4;
  const int klo = (l >> 4) << 4;
  const int e45 = klo ^ (swzc & 48);
  const int s6 = swzc & 64;
  const int kof0 = e45 | s6;
  const int kof1 = e45 | (64 ^ s6);

  i32x4 acc[8][4] = {};            // 128 acc regs
  i32x4 a[8], b0[4], b1[4];        // 64 frag regs

  const int NT = K >> 7;           // K-tiles of 128 (>=3)

#define WRAP(x) ((x) >= RING ? (x) - RING : (x))

#define LDA8R(base, dst) do {                                                 \
    const char* _b = sm + (base) + ln15 * 128;                                \
    _Pragma("unroll") for (int f = 0; f < 4; ++f) {                           \
      dst[f*2+0] = *(const i32x4*)(_b + f*2048 + kof0);                       \
      dst[f*2+1] = *(const i32x4*)(_b + f*2048 + kof1); } } while (0)

#define LDBLO(base, dst) do {                                                 \
    const char* _b = sm + (base) + ln15 * 128;                                \
    _Pragma("unroll") for (int nf = 0; nf < 2; ++nf) {                        \
      dst[nf*2+0] = *(const i32x4*)(_b + nf*2048 + kof0);                     \
      dst[nf*2+1] = *(const i32x4*)(_b + nf*2048 + kof1); } } while (0)

#define LDBHI(base, dst) do {                                                 \
    const char* _b = sm + (base) + 4096 + ln15 * 128;                         \
    _Pragma("unroll") for (int nf = 0; nf < 2; ++nf) {                        \
      dst[nf*2+0] = *(const i32x4*)(_b + nf*2048 + kof0);                     \
      dst[nf*2+1] = *(const i32x4*)(_b + nf*2048 + kof1); } } while (0)

// region row r = j*16 + w*8 + srow8 holds tile-local row (mh*64 + r) of A
// (or hh*64 + r of B); 4 gl_lds per wave per region.
#define STAGE_A(base, mh, tb) do {                                            \
    _Pragma("unroll") for (int j = 0; j < 4; ++j)                             \
      gl_lds16(Ag + (size_t)((mh)*64 + j*16) * ldkb + (tb),                   \
               sm + (base) + w * 1024 + j * 2048); } while (0)

#define STAGE_B(base, hh, tb) do {                                            \
    _Pragma("unroll") for (int j = 0; j < 4; ++j)                             \
      gl_lds16(Bg + (size_t)((hh)*64 + j*16) * ldkb + (tb),                   \
               sm + (base) + w * 1024 + j * 2048); } while (0)

#define MMAQ(mh, nh, av, bv) do {                                             \
    _Pragma("unroll") for (int f = 0; f < 4; ++f)                             \
    _Pragma("unroll") for (int nf = 0; nf < 2; ++nf)                          \
    _Pragma("unroll") for (int ks = 0; ks < 2; ++ks)                          \
      acc[(mh)*4+f][(nh)*2+nf] = __builtin_amdgcn_mfma_i32_16x16x64_i8(       \
          av[f*2+ks], bv[nf*2+ks], acc[(mh)*4+f][(nh)*2+nf], 0, 0, 0);        \
  } while (0)

#define BAR() do { __builtin_amdgcn_sched_barrier(0);                         \
    asm volatile("s_barrier" ::: "memory");                                   \
    __builtin_amdgcn_sched_barrier(0); } while (0)

#define VMW(n) asm volatile("s_waitcnt vmcnt(" #n ")" ::: "memory")

  // prologue: stage tile0 (A0@0,B0@1,B1@2,A1@3); retire A0,B0,B1; publish
  STAGE_A(0 * RSZ, 0, 0);
  STAGE_B(1 * RSZ, 0, 0);
  STAGE_B(2 * RSZ, 1, 0);
  STAGE_A(3 * RSZ, 1, 0);
  VMW(4);
  BAR();

  const int rBw0 = (1 + w) * RSZ;  // this wave's B region, tile 0

  // ---- t = 0 peel (no carry-in MMAQ(1,1)) ----
  {
    const size_t tb1 = 128;  // tile 1 byte offset
    // phi1
    LDA8R(0 * RSZ, a);
    LDBLO(rBw0, b0);
    STAGE_A(4 * RSZ, 0, tb1);      // A0(1) -> region 4
    // phi2
    BAR();
    MMAQ(0, 0, a, b0);
    LDBHI(rBw0, b1);
    STAGE_B(0 * RSZ, 0, tb1);      // B0(1) -> region 0
    // phi3
    VMW(8); BAR();                 // retires A1(0)
    MMAQ(0, 1, a, b1);
    LDA8R(3 * RSZ, a);
    STAGE_B(1 * RSZ, 1, tb1);      // B1(1) -> region 1
    // phi4
    BAR();
    MMAQ(1, 0, a, b0);
    STAGE_A(2 * RSZ, 1, tb1);      // A1(1) -> region 2
  }

  int rb = 4 * RSZ;  // tile1's A0 region

  // ---- main tiles t = 1 .. NT-2 ----
  for (int t = 1; t < NT - 1; ++t) {
    const int rA0 = rb, rB0 = WRAP(rb + RSZ), rB1 = WRAP(rb + 2 * RSZ);
    const int rA1 = WRAP(rb + 3 * RSZ), rN = WRAP(rb + 4 * RSZ);
    const int rBw = w ? rB1 : rB0;
    const size_t tbn = (size_t)(t + 1) << 7;
    // phi1
    VMW(4); BAR();                 // retires A0,B0,B1(t)
    MMAQ(1, 1, a, b1);             // tile t-1 carry
    LDA8R(rA0, a);
    LDBLO(rBw, b0);
    STAGE_A(rN, 0, tbn);
    // phi2
    BAR();
    MMAQ(0, 0, a, b0);
    LDBHI(rBw, b1);
    STAGE_B(rA0, 0, tbn);          // B0(t+1) -> rA0
    // phi3
    VMW(8); BAR();                 // retires A1(t)
    MMAQ(0, 1, a, b1);
    LDA8R(rA1, a);
    STAGE_B(rB0, 1, tbn);          // B1(t+1) -> rB0
    // phi4
    BAR();
    MMAQ(1, 0, a, b0);
    STAGE_A(rB1, 1, tbn);          // A1(t+1) -> rB1
    rb = rN;
  }

  // ---- tail t = NT-1 (no stages; draining) ----
  {
    const int rA0 = rb, rB0 = WRAP(rb + RSZ), rB1 = WRAP(rb + 2 * RSZ);
    const int rA1 = WRAP(rb + 3 * RSZ);
    const int rBw = w ? rB1 : rB0;
    // phi1
    VMW(4); BAR();
    MMAQ(1, 1, a, b1);
    LDA8R(rA0, a);
    LDBLO(rBw, b0);
    // phi2
    BAR();
    MMAQ(0, 0, a, b0);
    LDBHI(rBw, b1);
    // phi3
    VMW(0); BAR();                 // retires A1(NT-1)
    MMAQ(0, 1, a, b1);
    LDA8R(rA1, a);
    // phi4
    BAR();
    MMAQ(1, 0, a, b0);
  }
  MMAQ(1, 1, a, b1);               // final carry-out

  // epilogue: out = acc * rs[row] * scaler[col]
  // row = m0 + (mf>>2)*64 + (mf&3)*16 + (l>>4)*4 + j
  // col = n0 + w*64 + (ng>>1)*32 + (ng&1)*16 + ln15
  float scl[4];
#pragma unroll
  for (int ng = 0; ng < 4; ++ng)
    scl[ng] = scaler[n0 + w * 64 + (ng >> 1) * 32 + (ng & 1) * 16 + ln15];
  const int row0 = m0 + ((l >> 4) << 2);
  const int col0 = n0 + w * 64 + ln15;
#pragma unroll
  for (int mf = 0; mf < 8; ++mf) {
    const int rbase = row0 + (mf >> 2) * 64 + (mf & 3) * 16;
#pragma unroll
    for (int j = 0; j < 4; ++j) {
      const float dr = rs[rbase + j];
      float* cp = C + (size_t)(rbase + j) * N + col0;
#pragma unroll
      for (int ng = 0; ng < 4; ++ng)
        cp[(ng >> 1) * 32 + (ng & 1) * 16] =
            (float)acc[mf][ng][j] * dr * scl[ng];
    }
  }
#undef WRAP
#undef LDA8R
#undef LDBLO
#undef LDBHI
#undef STAGE_A
#undef STAGE_B
#undef MMAQ
#undef BAR
#undef VMW
}

// ---- x per-row quantize, K==4096 fast path: row held in 16 VGPRs ----------
__global__ __launch_bounds__(256) void qrow4k(const float* __restrict__ x,
                                              char* __restrict__ q,
                                              float* __restrict__ rs) {
  const int r = blockIdx.x;
  const float4* xr = (const float4*)(x + (size_t)r * 4096);
  const int tid = threadIdx.x;
  float4 v[4];
  float mx = 0.f;
#pragma unroll
  for (int i = 0; i < 4; ++i) {
    v[i] = xr[tid + 256 * i];
    mx = fmaxf(mx, fmaxf(fmaxf(fabsf(v[i].x), fabsf(v[i].y)),
                         fmaxf(fabsf(v[i].z), fabsf(v[i].w))));
  }
#pragma unroll
  for (int off = 32; off; off >>= 1) mx = fmaxf(mx, __shfl_down(mx, off));
  __shared__ float smx[4];
  __shared__ float sinv;
  if ((tid & 63) == 0) smx[tid >> 6] = mx;
  __syncthreads();
  if (tid == 0) {
    float m = fmaxf(fmaxf(smx[0], smx[1]), fmaxf(smx[2], smx[3]));
    rs[r] = m / 127.0f;
    sinv = (m > 0.f) ? 127.0f / m : 0.f;
  }
  __syncthreads();
  const float inv = sinv;
  uint32_t* qr = (uint32_t*)(q + (size_t)r * 4096);
#pragma unroll
  for (int i = 0; i < 4; ++i) {
    int a0 = (int)rintf(v[i].x * inv), a1 = (int)rintf(v[i].y * inv);
    int a2 = (int)rintf(v[i].z * inv), a3 = (int)rintf(v[i].w * inv);
    qr[tid + 256 * i] =
        (uint32_t)(a0 & 0xff) | ((uint32_t)(a1 & 0xff) << 8) |
        ((uint32_t)(a2 & 0xff) << 16) | ((uint32_t)(a3 & 0xff) << 24);
  }
}

// ---- general per-row quantize (2-pass), any K%4==0 -------------------------
__global__ __launch_bounds__(256) void qrow(const float* __restrict__ x,
                                            char* __restrict__ q,
                                            float* __restrict__ rs, int K) {
  const int r = blockIdx.x;
  const float* xr = x + (size_t)r * K;
  const int tid = threadIdx.x;
  const int n4 = K >> 2;
  float mx = 0.f;
  for (int i = tid; i < n4; i += 256) {
    float4 v = ((const float4*)xr)[i];
    mx = fmaxf(mx, fmaxf(fmaxf(fabsf(v.x), fabsf(v.y)),
                         fmaxf(fabsf(v.z), fabsf(v.w))));
  }
#pragma unroll
  for (int off = 32; off; off >>= 1) mx = fmaxf(mx, __shfl_down(mx, off));
  __shared__ float smx[4];
  __shared__ float sinv;
  if ((tid & 63) == 0) smx[tid >> 6] = mx;
  __syncthreads();
  if (tid == 0) {
    float m = fmaxf(fmaxf(smx[0], smx[1]), fmaxf(smx[2], smx[3]));
    rs[r] = m / 127.0f;
    sinv = (m > 0.f) ? 127.0f / m : 0.f;
  }
  __syncthreads();
  const float inv = sinv;
  uint32_t* qr = (uint32_t*)(q + (size_t)r * K);
  for (int i = tid; i < n4; i += 256) {
    float4 v = ((const float4*)xr)[i];
    int a0 = (int)rintf(v.x * inv), a1 = (int)rintf(v.y * inv);
    int a2 = (int)rintf(v.z * inv), a3 = (int)rintf(v.w * inv);
    qr[i] = (uint32_t)(a0 & 0xff) | ((uint32_t)(a1 & 0xff) << 8) |
            ((uint32_t)(a2 & 0xff) << 16) | ((uint32_t)(a3 & 0xff) << 24);
  }
}

// ---- w pack: int32 (0..126) -> i8, 16 per thread ---------------------------
__global__ void qw_pack(const int* __restrict__ wq, char* __restrict__ q,
                        long long n16) {
  long long i = (long long)blockIdx.x * blockDim.x + threadIdx.x;
  const long long stride = (long long)gridDim.x * blockDim.x;
  for (; i < n16; i += stride) {
    const int4* p = (const int4*)(wq + i * 16);
    uint32_t o[4];
#pragma unroll
    for (int k = 0; k < 4; ++k) {
      int4 v = p[k];
      o[k] = (uint32_t)(v.x & 0xff) | ((uint32_t)(v.y & 0xff) << 8) |
             ((uint32_t)(v.z & 0xff) << 16) | ((uint32_t)(v.w & 0xff) << 24);
    }
    uint4 pk = {o[0], o[1], o[2], o[3]};
    *(uint4*)(q + i * 16) = pk;
  }
}

// ---------------- fallback (no workspace needed, any shape) -----------------
#define FBM 128
#define FBN 128
#define FBK 32

__global__ __launch_bounds__(256) void gemm_fb(
    const float* __restrict__ A, const int* __restrict__ B,
    const float* __restrict__ scaler, float* __restrict__ C,
    int M, int N, int K) {
  __shared__ alignas(16) short As[FBM * FBK];
  __shared__ alignas(16) short Bs[FBN * FBK];

  const int tid = threadIdx.x;
  const int lane = tid & 63;
  const int wid = tid >> 6;
  const int wr = wid >> 1, wc = wid & 1;

  const int nwg = gridDim.x;
  const int ntn = N / FBN;
  int bid = blockIdx.x;
  int q = nwg / NXCD, r = nwg % NXCD;
  int xcd = bid % NXCD, idx = bid / NXCD;
  int swz = (xcd < r ? xcd * (q + 1) : r * (q + 1) + (xcd - r) * q) + idx;
  const int mt = swz / ntn, nt = swz % ntn;
  const int m0 = mt * FBM, n0 = nt * FBN;

  f32x4 acc[4][4] = {};
  const int kiters = K / FBK;

  for (int kt = 0; kt < kiters; ++kt) {
    const int k0 = kt * FBK;
    __syncthreads();
#pragma unroll
    for (int qq = 0; qq < 4; ++qq) {
      int chunk = qq * 256 + tid;
      int row = chunk >> 3;
      int c4 = (chunk & 7) * 4;
      float4 va = *(const float4*)&A[(size_t)(m0 + row) * K + k0 + c4];
      int4 vb = *(const int4*)&B[(size_t)(n0 + row) * K + k0 + c4];
      short4v wa, wb;
      wa[0] = bf16_bits(va.x); wa[1] = bf16_bits(va.y);
      wa[2] = bf16_bits(va.z); wa[3] = bf16_bits(va.w);
      wb[0] = bf16_bits((float)vb.x); wb[1] = bf16_bits((float)vb.y);
      wb[2] = bf16_bits((float)vb.z); wb[3] = bf16_bits((float)vb.w);
      *(short4v*)&As[row * FBK + c4] = wa;
      *(short4v*)&Bs[row * FBK + c4] = wb;
    }
    __syncthreads();
    const int ar = wr * 64 + (lane & 15);
    const int br = wc * 64 + (lane & 15);
    const int ko = (lane >> 4) * 8;
    typedef __attribute__((ext_vector_type(8))) short short8v;
    short8v av[4], bv[4];
#pragma unroll
    for (int i = 0; i < 4; ++i) {
      av[i] = *(const short8v*)&As[(ar + i * 16) * FBK + ko];
      bv[i] = *(const short8v*)&Bs[(br + i * 16) * FBK + ko];
    }
#pragma unroll
    for (int mi = 0; mi < 4; ++mi)
#pragma unroll
      for (int ni = 0; ni < 4; ++ni)
        acc[mi][ni] = __builtin_amdgcn_mfma_f32_16x16x32_bf16(
            av[mi], bv[ni], acc[mi][ni], 0, 0, 0);
  }

  float sc[4];
  const int cc0 = n0 + wc * 64 + (lane & 15);
#pragma unroll
  for (int ni = 0; ni < 4; ++ni) sc[ni] = scaler[cc0 + ni * 16];
  const int cr0 = m0 + wr * 64 + ((lane >> 4) << 2);
#pragma unroll
  for (int mi = 0; mi < 4; ++mi)
#pragma unroll
    for (int j = 0; j < 4; ++j) {
      float* crow = C + (size_t)(cr0 + mi * 16 + j) * N;
#pragma unroll
      for (int ni = 0; ni < 4; ++ni)
        crow[cc0 + ni * 16] = acc[mi][ni][j] * sc[ni];
    }
}

extern "C" void kernel_launch(void* const* d_in, const int* in_sizes, int n_in,
                              void* d_out, int out_size, void* d_ws,
                              size_t ws_size, hipStream_t stream) {
  const float* x = (const float*)d_in[0];       // [M][K] fp32
  const int* w = (const int*)d_in[1];           // [N][K] int32 (0..126)
  const float* sc = (const float*)d_in[2];      // [N] fp32
  float* out = (float*)d_out;                   // [M][N] fp32

  const long long xn = in_sizes[0];             // M*K
  const long long wn = in_sizes[1];             // N*K
  const int N = in_sizes[2];
  const int K = (int)(wn / N);
  const int M = (int)(xn / K);

  const size_t need = (size_t)xn + (size_t)wn + (size_t)M * 4;
  const bool okt = (M % 128 == 0) && (N % 128 == 0) && (K % 128 == 0) &&
                   (K >= 384) && (K % 4 == 0);

  if (ws_size >= need && okt) {
    char* xq = (char*)d_ws;                     // i8 x  [M][K]
    char* wq = xq + xn;                         // i8 w  [N][K]
    float* rs = (float*)(wq + wn);              // row scales [M]
    if (K == 4096)
      qrow4k<<<M, 256, 0, stream>>>(x, xq, rs);
    else
      qrow<<<M, 256, 0, stream>>>(x, xq, rs, K);
    qw_pack<<<2048, 256, 0, stream>>>(w, wq, wn / 16);
    const int grid = (M / 128) * (N / 128);
    gemm128i8<<<grid, 128, 0, stream>>>(xq, wq, rs, sc, out, M, N, K);
  } else {
    const int grid = (M / FBM) * (N / FBN);
    gemm_fb<<<grid, 256, 0, stream>>>(x, w, sc, out, M, N, K);
  }
}

// Round 15
// 470.176 us; speedup vs baseline: 1.1371x; 1.1371x over previous
//
#include <hip/hip_runtime.h>
#include <stdint.h>

// ---------------------------------------------------------------------------
// XlaQuantizedLinear: out[M,N] = (x[M,K] @ w[N,K]^T) * scaler[N]
// Round 15: r12 i8 GEMM (256x256, 8 waves, 5x16KB ring — race-proven) with
// phases MERGED 4->2 per K-tile (halves barrier/lgkm edges), + prepass fusion.
//
// 2-phase ledger (slots A0,B0,B1,A1 at regions (4t+j) mod 5; advance 4/tile):
//  P1(t): VMW(2);BAR; MMAQ(1,0)+(1,1)[t-1]; rd A0(t)->a(8),B0->b0(4),
//         B1->b1(4); st A0(t+1)->rN (2 loads)
//  P2(t): VMW(2);BAR; MMAQ(0,0)+(0,1)(t);   rd A1(t)->a(8);
//         st B0(t+1)->rA0, B1(t+1)->rB0, A1(t+1)->rB1 (6 loads)
// vmcnt: enter P1(t): in flight {A0(t):2, B0/B1/A1(t):6}=8 -> VMW(2)
//  retires A0,B0,B1(t) (read this phase), keeps A1(t). Enter P2(t):
//  {A1(t):2, A0(t+1):2}=4 -> VMW(2) retires A1(t). Steady.
// WAR (all gap>=1 phase + barrier, the r8/r11/r12-proven pattern):
//  A0(t+1)@P1(t) over A1(t-1) read P2(t-1): gap1. B0(t+1)@P2(t) over
//  A0(t) read P1(t): gap1. B1(t+1)@P2(t) over B0(t) read P1(t): gap1.
//  A1(t+1)@P2(t) over B1(t) read P1(t): gap1. (r9's race was gap-0.)
// Reg liveness (in-order issue, MFMA-before-read): P1 MMAQs use a=A1(t-1),
//  b0,b1(t-1) then reads overwrite; P2 MMAQs use a=A0(t),b0,b1(t) then
//  LDA8R overwrites a. Same 64 frag regs as r12.
// Prepass: single fused kernel (blocks [0,M) = row-quantize x; rest = pack w).
// ---------------------------------------------------------------------------

typedef __attribute__((ext_vector_type(4))) int i32x4;      // i8 frag & acc
typedef __attribute__((ext_vector_type(4))) short short4v;
typedef __attribute__((ext_vector_type(4))) float f32x4;

#define NXCD 8
#define RSZ 16384
#define RING 81920

__device__ __forceinline__ short bf16_bits(float f) {
  uint32_t u = __builtin_bit_cast(uint32_t, f);
  uint32_t r = (u + 0x7FFFu + ((u >> 16) & 1u)) >> 16;
  return (short)r;
}

__device__ __forceinline__ void gl_lds16(const void* g, void* l) {
  __builtin_amdgcn_global_load_lds(
      (const __attribute__((address_space(1))) void*)g,
      (__attribute__((address_space(3))) void*)l, 16, 0, 0);
}

__global__ __launch_bounds__(512, 2) void gemm256i8(
    const char* __restrict__ A, const char* __restrict__ B,
    const float* __restrict__ rs, const float* __restrict__ scaler,
    float* __restrict__ C, int M, int N, int K) {
  __shared__ alignas(16) char sm[RING];  // 80 KB

  const int tid = threadIdx.x;
  const int l = tid & 63;
  const int w = tid >> 6;
  const int wr = w >> 2, wc = w & 3;
  const int ln15 = l & 15;

  // bijective XCD-aware swizzle (m204)
  const int nwg = gridDim.x;
  const int ntn = N >> 8;
  int bid = blockIdx.x;
  int q = nwg / NXCD, rr = nwg % NXCD;
  int xcd = bid % NXCD, idx = bid / NXCD;
  int swz = (xcd < rr ? xcd * (q + 1) : rr * (q + 1) + (xcd - rr) * q) + idx;
  const int m0 = (swz / ntn) << 8, n0 = (swz % ntn) << 8;

  const size_t ldkb = (size_t)K;   // bytes per row (i8)

  // staging per-thread bases (source pre-swizzled: rule 21)
  const int srow8 = l >> 3;
  const int sswz = ((l & 7) ^ srow8) << 4;
  const char* Ag = A + (size_t)(m0 + w * 8 + srow8) * ldkb + sswz;
  const char* Bg = B + (size_t)(n0 + (w >> 2) * 64 + (w & 3) * 8 + srow8) * ldkb + sswz;

  // read-side swizzled k offsets
  const int swzc = (l & 7) << 4;
  const int klo = (l >> 4) << 4;
  const int e45 = klo ^ (swzc & 48);
  const int s6 = swzc & 64;
  const int kof0 = e45 | s6;
  const int kof1 = e45 | (64 ^ s6);

  i32x4 acc[8][4] = {};
  i32x4 a[8], b0[4], b1[4];

  const int NT = K >> 7;            // K-tiles of 128 (>=3)

#define WRAP(x) ((x) >= RING ? (x) - RING : (x))

#define LDA8R(base, dst) do {                                                 \
    const char* _b = sm + (base) + (wr * 64 + ln15) * 128;                    \
    _Pragma("unroll") for (int f = 0; f < 4; ++f) {                           \
      dst[f*2+0] = *(const i32x4*)(_b + f*2048 + kof0);                       \
      dst[f*2+1] = *(const i32x4*)(_b + f*2048 + kof1); } } while (0)

#define LDB4R(base, dst) do {                                                 \
    const char* _b = sm + (base) + (wc * 32 + ln15) * 128;                    \
    _Pragma("unroll") for (int nf = 0; nf < 2; ++nf) {                        \
      dst[nf*2+0] = *(const i32x4*)(_b + nf*2048 + kof0);                     \
      dst[nf*2+1] = *(const i32x4*)(_b + nf*2048 + kof1); } } while (0)

#define STAGE_A(base, mh, tb) do {                                            \
    gl_lds16(Ag + (size_t)((mh)*64) * ldkb + (tb),                            \
             sm + (base) + w * 1024);                                         \
    gl_lds16(Ag + (size_t)((mh)*64 + 128) * ldkb + (tb),                      \
             sm + (base) + 8192 + w * 1024); } while (0)

#define STAGE_B(base, nh, tb) do {                                            \
    gl_lds16(Bg + (size_t)((nh)*32) * ldkb + (tb),                            \
             sm + (base) + w * 1024);                                         \
    gl_lds16(Bg + (size_t)((nh)*32 + 128) * ldkb + (tb),                      \
             sm + (base) + 8192 + w * 1024); } while (0)

#define MMAQ(mh, nh, av, bv) do {                                             \
    _Pragma("unroll") for (int f = 0; f < 4; ++f)                             \
    _Pragma("unroll") for (int nf = 0; nf < 2; ++nf)                          \
    _Pragma("unroll") for (int ks = 0; ks < 2; ++ks)                          \
      acc[(mh)*4+f][(nh)*2+nf] = __builtin_amdgcn_mfma_i32_16x16x64_i8(       \
          av[f*2+ks], bv[nf*2+ks], acc[(mh)*4+f][(nh)*2+nf], 0, 0, 0);        \
  } while (0)

#define BAR() do { __builtin_amdgcn_sched_barrier(0);                         \
    asm volatile("s_barrier" ::: "memory");                                   \
    __builtin_amdgcn_sched_barrier(0); } while (0)

#define VMW(n) asm volatile("s_waitcnt vmcnt(" #n ")" ::: "memory")

  // prologue: stage tile0 (A0@0,B0@1,B1@2,A1@3); retire A0,B0,B1; publish
  STAGE_A(0 * RSZ, 0, 0);
  STAGE_B(1 * RSZ, 0, 0);
  STAGE_B(2 * RSZ, 1, 0);
  STAGE_A(3 * RSZ, 1, 0);
  VMW(2);                          // keep A1(0)'s 2 in flight
  BAR();

  // ---- t = 0 peel (no carry-in MMAQs) ----
  {
    const size_t tb1 = 128;  // tile 1 byte offset
    // P1(0)
    LDA8R(0 * RSZ, a);
    LDB4R(1 * RSZ, b0);
    LDB4R(2 * RSZ, b1);
    STAGE_A(4 * RSZ, 0, tb1);      // A0(1) -> region 4 (free)
    // P2(0)
    VMW(2); BAR();                 // retires A1(0); keeps A0(1)
    MMAQ(0, 0, a, b0);
    MMAQ(0, 1, a, b1);
    LDA8R(3 * RSZ, a);             // A1(0)
    STAGE_B(0 * RSZ, 0, tb1);      // B0(1) -> region0 (A0(0) read P1(0), gap1)
    STAGE_B(1 * RSZ, 1, tb1);      // B1(1) -> region1 (B0(0) read P1(0), gap1)
    STAGE_A(2 * RSZ, 1, tb1);      // A1(1) -> region2 (B1(0) read P1(0), gap1)
  }

  int rb = 4 * RSZ;  // tile1's A0 region

  // ---- main tiles t = 1 .. NT-2 ----
  for (int t = 1; t < NT - 1; ++t) {
    const int rA0 = rb, rB0 = WRAP(rb + RSZ), rB1 = WRAP(rb + 2 * RSZ);
    const int rA1 = WRAP(rb + 3 * RSZ), rN = WRAP(rb + 4 * RSZ);
    const size_t tbn = (size_t)(t + 1) << 7;
    // P1
    VMW(2); BAR();                 // retires A0,B0,B1(t); keeps A1(t)
    MMAQ(1, 0, a, b0);             // tile t-1 carry (a=A1(t-1))
    MMAQ(1, 1, a, b1);
    LDA8R(rA0, a);
    LDB4R(rB0, b0);
    LDB4R(rB1, b1);
    STAGE_A(rN, 0, tbn);           // A0(t+1) over A1(t-1) (read P2(t-1), gap1)
    // P2
    VMW(2); BAR();                 // retires A1(t); keeps A0(t+1)
    MMAQ(0, 0, a, b0);
    MMAQ(0, 1, a, b1);
    LDA8R(rA1, a);                 // A1(t)
    STAGE_B(rA0, 0, tbn);          // B0(t+1) over A0(t) (read P1(t), gap1)
    STAGE_B(rB0, 1, tbn);          // B1(t+1) over B0(t) (read P1(t), gap1)
    STAGE_A(rB1, 1, tbn);          // A1(t+1) over B1(t) (read P1(t), gap1)
    rb = rN;
  }

  // ---- tail t = NT-1 (no stages; draining) ----
  {
    const int rA0 = rb, rB0 = WRAP(rb + RSZ), rB1 = WRAP(rb + 2 * RSZ);
    const int rA1 = WRAP(rb + 3 * RSZ);
    // P1
    VMW(2); BAR();
    MMAQ(1, 0, a, b0);
    MMAQ(1, 1, a, b1);
    LDA8R(rA0, a);
    LDB4R(rB0, b0);
    LDB4R(rB1, b1);
    // P2
    VMW(0); BAR();                 // drain A1(NT-1)
    MMAQ(0, 0, a, b0);
    MMAQ(0, 1, a, b1);
    LDA8R(rA1, a);
    MMAQ(1, 0, a, b0);             // final carry-out (compiler lgkm-waits a)
    MMAQ(1, 1, a, b1);
  }

  // epilogue: out = acc * rs[row] * scaler[col]
  float scl[4];
#pragma unroll
  for (int ng = 0; ng < 4; ++ng)
    scl[ng] = scaler[n0 + wc * 64 + (ng >> 1) * 32 + (ng & 1) * 16 + ln15];
  const int row0 = m0 + wr * 128 + ((l >> 4) << 2);
  const int col0 = n0 + wc * 64 + ln15;
#pragma unroll
  for (int mf = 0; mf < 8; ++mf) {
    const int rbase = row0 + (mf >> 2) * 64 + (mf & 3) * 16;
#pragma unroll
    for (int j = 0; j < 4; ++j) {
      const float dr = rs[rbase + j];
      float* cp = C + (size_t)(rbase + j) * N + col0;
#pragma unroll
      for (int ng = 0; ng < 4; ++ng)
        cp[(ng >> 1) * 32 + (ng & 1) * 16] =
            (float)acc[mf][ng][j] * dr * scl[ng];
    }
  }
#undef WRAP
#undef LDA8R
#undef LDB4R
#undef STAGE_A
#undef STAGE_B
#undef MMAQ
#undef BAR
#undef VMW
}

// ---- fused prepass (K==4096): blocks [0,M) quantize x rows; rest pack w ----
__global__ __launch_bounds__(256) void prep4k(
    const float* __restrict__ x, const int* __restrict__ wsrc,
    char* __restrict__ xq, char* __restrict__ wq,
    float* __restrict__ rs, int M, long long nw16) {
  const int tid = threadIdx.x;
  if ((int)blockIdx.x < M) {
    const int r = blockIdx.x;
    const float4* xr = (const float4*)(x + (size_t)r * 4096);
    float4 v[4];
    float mx = 0.f;
#pragma unroll
    for (int i = 0; i < 4; ++i) {
      v[i] = xr[tid + 256 * i];
      mx = fmaxf(mx, fmaxf(fmaxf(fabsf(v[i].x), fabsf(v[i].y)),
                           fmaxf(fabsf(v[i].z), fabsf(v[i].w))));
    }
#pragma unroll
    for (int off = 32; off; off >>= 1) mx = fmaxf(mx, __shfl_down(mx, off));
    __shared__ float smx[4];
    __shared__ float sinv;
    if ((tid & 63) == 0) smx[tid >> 6] = mx;
    __syncthreads();
    if (tid == 0) {
      float m = fmaxf(fmaxf(smx[0], smx[1]), fmaxf(smx[2], smx[3]));
      rs[r] = m / 127.0f;
      sinv = (m > 0.f) ? 127.0f / m : 0.f;
    }
    __syncthreads();
    const float inv = sinv;
    uint32_t* qr = (uint32_t*)(xq + (size_t)r * 4096);
#pragma unroll
    for (int i = 0; i < 4; ++i) {
      int a0 = (int)rintf(v[i].x * inv), a1 = (int)rintf(v[i].y * inv);
      int a2 = (int)rintf(v[i].z * inv), a3 = (int)rintf(v[i].w * inv);
      qr[tid + 256 * i] =
          (uint32_t)(a0 & 0xff) | ((uint32_t)(a1 & 0xff) << 8) |
          ((uint32_t)(a2 & 0xff) << 16) | ((uint32_t)(a3 & 0xff) << 24);
    }
  } else {
    const long long nblk = (long long)gridDim.x - M;
    long long i = (long long)(blockIdx.x - M) * 256 + tid;
    const long long stride = nblk * 256;
    for (; i < nw16; i += stride) {
      const int4* p = (const int4*)(wsrc + i * 16);
      uint32_t o[4];
#pragma unroll
      for (int k = 0; k < 4; ++k) {
        int4 v = p[k];
        o[k] = (uint32_t)(v.x & 0xff) | ((uint32_t)(v.y & 0xff) << 8) |
               ((uint32_t)(v.z & 0xff) << 16) | ((uint32_t)(v.w & 0xff) << 24);
      }
      uint4 pk = {o[0], o[1], o[2], o[3]};
      *(uint4*)(wq + i * 16) = pk;
    }
  }
}

// ---- general per-row quantize (2-pass), any K%4==0 -------------------------
__global__ __launch_bounds__(256) void qrow(const float* __restrict__ x,
                                            char* __restrict__ q,
                                            float* __restrict__ rs, int K) {
  const int r = blockIdx.x;
  const float* xr = x + (size_t)r * K;
  const int tid = threadIdx.x;
  const int n4 = K >> 2;
  float mx = 0.f;
  for (int i = tid; i < n4; i += 256) {
    float4 v = ((const float4*)xr)[i];
    mx = fmaxf(mx, fmaxf(fmaxf(fabsf(v.x), fabsf(v.y)),
                         fmaxf(fabsf(v.z), fabsf(v.w))));
  }
#pragma unroll
  for (int off = 32; off; off >>= 1) mx = fmaxf(mx, __shfl_down(mx, off));
  __shared__ float smx[4];
  __shared__ float sinv;
  if ((tid & 63) == 0) smx[tid >> 6] = mx;
  __syncthreads();
  if (tid == 0) {
    float m = fmaxf(fmaxf(smx[0], smx[1]), fmaxf(smx[2], smx[3]));
    rs[r] = m / 127.0f;
    sinv = (m > 0.f) ? 127.0f / m : 0.f;
  }
  __syncthreads();
  const float inv = sinv;
  uint32_t* qr = (uint32_t*)(q + (size_t)r * K);
  for (int i = tid; i < n4; i += 256) {
    float4 v = ((const float4*)xr)[i];
    int a0 = (int)rintf(v.x * inv), a1 = (int)rintf(v.y * inv);
    int a2 = (int)rintf(v.z * inv), a3 = (int)rintf(v.w * inv);
    qr[i] = (uint32_t)(a0 & 0xff) | ((uint32_t)(a1 & 0xff) << 8) |
            ((uint32_t)(a2 & 0xff) << 16) | ((uint32_t)(a3 & 0xff) << 24);
  }
}

// ---- w pack (general path) -------------------------------------------------
__global__ void qw_pack(const int* __restrict__ wq, char* __restrict__ q,
                        long long n16) {
  long long i = (long long)blockIdx.x * blockDim.x + threadIdx.x;
  const long long stride = (long long)gridDim.x * blockDim.x;
  for (; i < n16; i += stride) {
    const int4* p = (const int4*)(wq + i * 16);
    uint32_t o[4];
#pragma unroll
    for (int k = 0; k < 4; ++k) {
      int4 v = p[k];
      o[k] = (uint32_t)(v.x & 0xff) | ((uint32_t)(v.y & 0xff) << 8) |
             ((uint32_t)(v.z & 0xff) << 16) | ((uint32_t)(v.w & 0xff) << 24);
    }
    uint4 pk = {o[0], o[1], o[2], o[3]};
    *(uint4*)(q + i * 16) = pk;
  }
}

// ---------------- fallback (no workspace needed, any shape) -----------------
#define FBM 128
#define FBN 128
#define FBK 32

__global__ __launch_bounds__(256) void gemm_fb(
    const float* __restrict__ A, const int* __restrict__ B,
    const float* __restrict__ scaler, float* __restrict__ C,
    int M, int N, int K) {
  __shared__ alignas(16) short As[FBM * FBK];
  __shared__ alignas(16) short Bs[FBN * FBK];

  const int tid = threadIdx.x;
  const int lane = tid & 63;
  const int wid = tid >> 6;
  const int wr = wid >> 1, wc = wid & 1;

  const int nwg = gridDim.x;
  const int ntn = N / FBN;
  int bid = blockIdx.x;
  int q = nwg / NXCD, r = nwg % NXCD;
  int xcd = bid % NXCD, idx = bid / NXCD;
  int swz = (xcd < r ? xcd * (q + 1) : r * (q + 1) + (xcd - r) * q) + idx;
  const int mt = swz / ntn, nt = swz % ntn;
  const int m0 = mt * FBM, n0 = nt * FBN;

  f32x4 acc[4][4] = {};
  const int kiters = K / FBK;

  for (int kt = 0; kt < kiters; ++kt) {
    const int k0 = kt * FBK;
    __syncthreads();
#pragma unroll
    for (int qq = 0; qq < 4; ++qq) {
      int chunk = qq * 256 + tid;
      int row = chunk >> 3;
      int c4 = (chunk & 7) * 4;
      float4 va = *(const float4*)&A[(size_t)(m0 + row) * K + k0 + c4];
      int4 vb = *(const int4*)&B[(size_t)(n0 + row) * K + k0 + c4];
      short4v wa, wb;
      wa[0] = bf16_bits(va.x); wa[1] = bf16_bits(va.y);
      wa[2] = bf16_bits(va.z); wa[3] = bf16_bits(va.w);
      wb[0] = bf16_bits((float)vb.x); wb[1] = bf16_bits((float)vb.y);
      wb[2] = bf16_bits((float)vb.z); wb[3] = bf16_bits((float)vb.w);
      *(short4v*)&As[row * FBK + c4] = wa;
      *(short4v*)&Bs[row * FBK + c4] = wb;
    }
    __syncthreads();
    const int ar = wr * 64 + (lane & 15);
    const int br = wc * 64 + (lane & 15);
    const int ko = (lane >> 4) * 8;
    typedef __attribute__((ext_vector_type(8))) short short8v;
    short8v av[4], bv[4];
#pragma unroll
    for (int i = 0; i < 4; ++i) {
      av[i] = *(const short8v*)&As[(ar + i * 16) * FBK + ko];
      bv[i] = *(const short8v*)&Bs[(br + i * 16) * FBK + ko];
    }
#pragma unroll
    for (int mi = 0; mi < 4; ++mi)
#pragma unroll
      for (int ni = 0; ni < 4; ++ni)
        acc[mi][ni] = __builtin_amdgcn_mfma_f32_16x16x32_bf16(
            av[mi], bv[ni], acc[mi][ni], 0, 0, 0);
  }

  float sc[4];
  const int cc0 = n0 + wc * 64 + (lane & 15);
#pragma unroll
  for (int ni = 0; ni < 4; ++ni) sc[ni] = scaler[cc0 + ni * 16];
  const int cr0 = m0 + wr * 64 + ((lane >> 4) << 2);
#pragma unroll
  for (int mi = 0; mi < 4; ++mi)
#pragma unroll
    for (int j = 0; j < 4; ++j) {
      float* crow = C + (size_t)(cr0 + mi * 16 + j) * N;
#pragma unroll
      for (int ni = 0; ni < 4; ++ni)
        crow[cc0 + ni * 16] = acc[mi][ni][j] * sc[ni];
    }
}

extern "C" void kernel_launch(void* const* d_in, const int* in_sizes, int n_in,
                              void* d_out, int out_size, void* d_ws,
                              size_t ws_size, hipStream_t stream) {
  const float* x = (const float*)d_in[0];       // [M][K] fp32
  const int* w = (const int*)d_in[1];           // [N][K] int32 (0..126)
  const float* sc = (const float*)d_in[2];      // [N] fp32
  float* out = (float*)d_out;                   // [M][N] fp32

  const long long xn = in_sizes[0];             // M*K
  const long long wn = in_sizes[1];             // N*K
  const int N = in_sizes[2];
  const int K = (int)(wn / N);
  const int M = (int)(xn / K);

  const size_t need = (size_t)xn + (size_t)wn + (size_t)M * 4;
  const bool okt = (M % 256 == 0) && (N % 256 == 0) && (K % 128 == 0) &&
                   (K >= 384) && (K % 4 == 0);

  if (ws_size >= need && okt) {
    char* xq = (char*)d_ws;                     // i8 x  [M][K]
    char* wq = xq + xn;                         // i8 w  [N][K]
    float* rs = (float*)(wq + wn);              // row scales [M]
    if (K == 4096) {
      prep4k<<<M + 2048, 256, 0, stream>>>(x, w, xq, wq, rs, M, wn / 16);
    } else {
      qrow<<<M, 256, 0, stream>>>(x, xq, rs, K);
      qw_pack<<<2048, 256, 0, stream>>>(w, wq, wn / 16);
    }
    const int grid = (M / 256) * (N / 256);
    gemm256i8<<<grid, 512, 0, stream>>>(xq, wq, rs, sc, out, M, N, K);
  } else {
    const int grid = (M / FBM) * (N / FBN);
    gemm_fb<<<grid, 256, 0, stream>>>(x, w, sc, out, M, N, K);
  }
}

// Round 16
// 433.265 us; speedup vs baseline: 1.2340x; 1.0852x over previous
//
#include <hip/hip_runtime.h>
#include <stdint.h>

// ---------------------------------------------------------------------------
// XlaQuantizedLinear: out[M,N] = (x[M,K] @ w[N,K]^T) * scaler[N]
// Round 16 (consolidation): r12 i8 GEMM byte-identical (best measured:
// 356us, MfmaUtil 47, race-clean across replay re-validation) + r15's fused
// single-launch prepass (proven -21us). r15's 2-phase merge regressed
// (lead shrank below HBM latency) and is reverted.
//
// GEMM structure (r12): 256x256 tile, 8 waves, 16x16x64 i8 MFMA, BK=128,
// 5x16KB LDS ring, 4 phases/K-tile, balanced reads 8/4/8/4 b128/wave,
// counted vmcnt 4/4/4/2, XOR-swizzled LDS both-sides, bijective XCD swizzle.
//  phase | VMW | MMAQ (carry)   | read (after MMAQ)   | stage
//  phi1  |  4  | (1,1)[t-1]     | A0(t)->a   (8)      | A0(t+1)->rN
//  phi2  |  4  | (0,0)          | B1(t)->b1  (4)      | B0(t+1)->rA0
//  phi3  |  4  | (0,1)          | A1(t)->a   (8)      | B1(t+1)->rB0
//  phi4  |  2  | (1,0)          | B0(t+1)->b0 (4)     | A1(t+1)->rB1
// ---------------------------------------------------------------------------

typedef __attribute__((ext_vector_type(4))) int i32x4;      // i8 frag & acc
typedef __attribute__((ext_vector_type(4))) short short4v;
typedef __attribute__((ext_vector_type(4))) float f32x4;

#define NXCD 8
#define RSZ 16384
#define RING 81920

__device__ __forceinline__ short bf16_bits(float f) {
  uint32_t u = __builtin_bit_cast(uint32_t, f);
  uint32_t r = (u + 0x7FFFu + ((u >> 16) & 1u)) >> 16;
  return (short)r;
}

__device__ __forceinline__ void gl_lds16(const void* g, void* l) {
  __builtin_amdgcn_global_load_lds(
      (const __attribute__((address_space(1))) void*)g,
      (__attribute__((address_space(3))) void*)l, 16, 0, 0);
}

__global__ __launch_bounds__(512, 2) void gemm256i8(
    const char* __restrict__ A, const char* __restrict__ B,
    const float* __restrict__ rs, const float* __restrict__ scaler,
    float* __restrict__ C, int M, int N, int K) {
  __shared__ alignas(16) char sm[RING];  // 80 KB

  const int tid = threadIdx.x;
  const int l = tid & 63;
  const int w = tid >> 6;
  const int wr = w >> 2, wc = w & 3;
  const int ln15 = l & 15;

  // bijective XCD-aware swizzle (m204)
  const int nwg = gridDim.x;
  const int ntn = N >> 8;
  int bid = blockIdx.x;
  int q = nwg / NXCD, rr = nwg % NXCD;
  int xcd = bid % NXCD, idx = bid / NXCD;
  int swz = (xcd < rr ? xcd * (q + 1) : rr * (q + 1) + (xcd - rr) * q) + idx;
  const int m0 = (swz / ntn) << 8, n0 = (swz % ntn) << 8;

  const size_t ldkb = (size_t)K;   // bytes per row (i8)

  // staging per-thread bases (source pre-swizzled: rule 21)
  const int srow8 = l >> 3;
  const int sswz = ((l & 7) ^ srow8) << 4;
  const char* Ag = A + (size_t)(m0 + w * 8 + srow8) * ldkb + sswz;
  const char* Bg = B + (size_t)(n0 + (w >> 2) * 64 + (w & 3) * 8 + srow8) * ldkb + sswz;

  // read-side swizzled k offsets
  const int swzc = (l & 7) << 4;
  const int klo = (l >> 4) << 4;
  const int e45 = klo ^ (swzc & 48);
  const int s6 = swzc & 64;
  const int kof0 = e45 | s6;
  const int kof1 = e45 | (64 ^ s6);

  i32x4 acc[8][4] = {};
  i32x4 a[8], b0[4], b1[4];

  const int NT = K >> 7;            // K-tiles of 128 (>=3)

#define WRAP(x) ((x) >= RING ? (x) - RING : (x))

#define LDA8R(base, dst) do {                                                 \
    const char* _b = sm + (base) + (wr * 64 + ln15) * 128;                    \
    _Pragma("unroll") for (int f = 0; f < 4; ++f) {                           \
      dst[f*2+0] = *(const i32x4*)(_b + f*2048 + kof0);                       \
      dst[f*2+1] = *(const i32x4*)(_b + f*2048 + kof1); } } while (0)

#define LDB4R(base, dst) do {                                                 \
    const char* _b = sm + (base) + (wc * 32 + ln15) * 128;                    \
    _Pragma("unroll") for (int nf = 0; nf < 2; ++nf) {                        \
      dst[nf*2+0] = *(const i32x4*)(_b + nf*2048 + kof0);                     \
      dst[nf*2+1] = *(const i32x4*)(_b + nf*2048 + kof1); } } while (0)

#define STAGE_A(base, mh, tb) do {                                            \
    gl_lds16(Ag + (size_t)((mh)*64) * ldkb + (tb),                            \
             sm + (base) + w * 1024);                                         \
    gl_lds16(Ag + (size_t)((mh)*64 + 128) * ldkb + (tb),                      \
             sm + (base) + 8192 + w * 1024); } while (0)

#define STAGE_B(base, nh, tb) do {                                            \
    gl_lds16(Bg + (size_t)((nh)*32) * ldkb + (tb),                            \
             sm + (base) + w * 1024);                                         \
    gl_lds16(Bg + (size_t)((nh)*32 + 128) * ldkb + (tb),                      \
             sm + (base) + 8192 + w * 1024); } while (0)

#define MMAQ(mh, nh, av, bv) do {                                             \
    _Pragma("unroll") for (int f = 0; f < 4; ++f)                             \
    _Pragma("unroll") for (int nf = 0; nf < 2; ++nf)                          \
    _Pragma("unroll") for (int ks = 0; ks < 2; ++ks)                          \
      acc[(mh)*4+f][(nh)*2+nf] = __builtin_amdgcn_mfma_i32_16x16x64_i8(       \
          av[f*2+ks], bv[nf*2+ks], acc[(mh)*4+f][(nh)*2+nf], 0, 0, 0);        \
  } while (0)

#define BAR() do { __builtin_amdgcn_sched_barrier(0);                         \
    asm volatile("s_barrier" ::: "memory");                                   \
    __builtin_amdgcn_sched_barrier(0); } while (0)

#define VMW(n) asm volatile("s_waitcnt vmcnt(" #n ")" ::: "memory")

  // prologue: stage tile0 (A0@0,B0@1,B1@2,A1@3); retire A0,B0; publish
  STAGE_A(0 * RSZ, 0, 0);
  STAGE_B(1 * RSZ, 0, 0);
  STAGE_B(2 * RSZ, 1, 0);
  STAGE_A(3 * RSZ, 1, 0);
  VMW(4);
  BAR();

  // ---- t = 0 peel ----
  {
    const size_t tb1 = 128;  // tile 1 byte offset
    // "phi4(-1)" read + phi1(0): no carry MMAQ
    LDB4R(1 * RSZ, b0);            // B0(0)
    LDA8R(0 * RSZ, a);             // A0(0)
    STAGE_A(4 * RSZ, 0, tb1);      // A0(1) -> region 4
    // phi2(0)
    VMW(4); BAR();                 // retires B1(0)
    MMAQ(0, 0, a, b0);
    LDB4R(2 * RSZ, b1);            // B1(0)
    STAGE_B(0 * RSZ, 0, tb1);      // B0(1) -> region 0
    // phi3(0)
    VMW(4); BAR();                 // retires A1(0)
    MMAQ(0, 1, a, b1);
    LDA8R(3 * RSZ, a);             // A1(0)
    STAGE_B(1 * RSZ, 1, tb1);      // B1(1) -> region 1
    // phi4(0)
    VMW(2); BAR();                 // retires A0(1),B0(1)
    MMAQ(1, 0, a, b0);
    LDB4R(0 * RSZ, b0);            // B0(1)
    STAGE_A(2 * RSZ, 1, tb1);      // A1(1) -> region 2
  }

  int rb = 4 * RSZ;  // tile1's A0 region

  // ---- main tiles t = 1 .. NT-2 ----
  for (int t = 1; t < NT - 1; ++t) {
    const int rA0 = rb, rB0 = WRAP(rb + RSZ), rB1 = WRAP(rb + 2 * RSZ);
    const int rA1 = WRAP(rb + 3 * RSZ), rN = WRAP(rb + 4 * RSZ);
    const size_t tbn = (size_t)(t + 1) << 7;
    // phi1
    VMW(4); BAR();
    MMAQ(1, 1, a, b1);             // tile t-1 carry
    LDA8R(rA0, a);                 // A0(t)
    STAGE_A(rN, 0, tbn);
    // phi2
    VMW(4); BAR();                 // retires B1(t)
    MMAQ(0, 0, a, b0);
    LDB4R(rB1, b1);                // B1(t)
    STAGE_B(rA0, 0, tbn);          // B0(t+1) -> rA0
    // phi3
    VMW(4); BAR();                 // retires A1(t)
    MMAQ(0, 1, a, b1);
    LDA8R(rA1, a);                 // A1(t)
    STAGE_B(rB0, 1, tbn);
    // phi4
    VMW(2); BAR();                 // retires A0(t+1),B0(t+1)
    MMAQ(1, 0, a, b0);
    LDB4R(rA0, b0);                // B0(t+1)
    STAGE_A(rB1, 1, tbn);
    rb = rN;
  }

  // ---- tail t = NT-1 (no stages; draining) ----
  {
    const int rA0 = rb, rB1 = WRAP(rb + 2 * RSZ), rA1 = WRAP(rb + 3 * RSZ);
    // phi1
    VMW(4); BAR();
    MMAQ(1, 1, a, b1);
    LDA8R(rA0, a);
    // phi2
    VMW(2); BAR();                 // retires B1(NT-1)
    MMAQ(0, 0, a, b0);
    LDB4R(rB1, b1);
    // phi3
    VMW(0); BAR();                 // retires A1(NT-1)
    MMAQ(0, 1, a, b1);
    LDA8R(rA1, a);
    // phi4
    BAR();
    MMAQ(1, 0, a, b0);
  }
  MMAQ(1, 1, a, b1);               // final carry-out

  // epilogue: out = acc * rs[row] * scaler[col]
  float scl[4];
#pragma unroll
  for (int ng = 0; ng < 4; ++ng)
    scl[ng] = scaler[n0 + wc * 64 + (ng >> 1) * 32 + (ng & 1) * 16 + ln15];
  const int row0 = m0 + wr * 128 + ((l >> 4) << 2);
  const int col0 = n0 + wc * 64 + ln15;
#pragma unroll
  for (int mf = 0; mf < 8; ++mf) {
    const int rbase = row0 + (mf >> 2) * 64 + (mf & 3) * 16;
#pragma unroll
    for (int j = 0; j < 4; ++j) {
      const float dr = rs[rbase + j];
      float* cp = C + (size_t)(rbase + j) * N + col0;
#pragma unroll
      for (int ng = 0; ng < 4; ++ng)
        cp[(ng >> 1) * 32 + (ng & 1) * 16] =
            (float)acc[mf][ng][j] * dr * scl[ng];
    }
  }
#undef WRAP
#undef LDA8R
#undef LDB4R
#undef STAGE_A
#undef STAGE_B
#undef MMAQ
#undef BAR
#undef VMW
}

// ---- fused prepass (K==4096): blocks [0,M) quantize x rows; rest pack w ----
__global__ __launch_bounds__(256) void prep4k(
    const float* __restrict__ x, const int* __restrict__ wsrc,
    char* __restrict__ xq, char* __restrict__ wq,
    float* __restrict__ rs, int M, long long nw16) {
  const int tid = threadIdx.x;
  if ((int)blockIdx.x < M) {
    const int r = blockIdx.x;
    const float4* xr = (const float4*)(x + (size_t)r * 4096);
    float4 v[4];
    float mx = 0.f;
#pragma unroll
    for (int i = 0; i < 4; ++i) {
      v[i] = xr[tid + 256 * i];
      mx = fmaxf(mx, fmaxf(fmaxf(fabsf(v[i].x), fabsf(v[i].y)),
                           fmaxf(fabsf(v[i].z), fabsf(v[i].w))));
    }
#pragma unroll
    for (int off = 32; off; off >>= 1) mx = fmaxf(mx, __shfl_down(mx, off));
    __shared__ float smx[4];
    __shared__ float sinv;
    if ((tid & 63) == 0) smx[tid >> 6] = mx;
    __syncthreads();
    if (tid == 0) {
      float m = fmaxf(fmaxf(smx[0], smx[1]), fmaxf(smx[2], smx[3]));
      rs[r] = m / 127.0f;
      sinv = (m > 0.f) ? 127.0f / m : 0.f;
    }
    __syncthreads();
    const float inv = sinv;
    uint32_t* qr = (uint32_t*)(xq + (size_t)r * 4096);
#pragma unroll
    for (int i = 0; i < 4; ++i) {
      int a0 = (int)rintf(v[i].x * inv), a1 = (int)rintf(v[i].y * inv);
      int a2 = (int)rintf(v[i].z * inv), a3 = (int)rintf(v[i].w * inv);
      qr[tid + 256 * i] =
          (uint32_t)(a0 & 0xff) | ((uint32_t)(a1 & 0xff) << 8) |
          ((uint32_t)(a2 & 0xff) << 16) | ((uint32_t)(a3 & 0xff) << 24);
    }
  } else {
    const long long nblk = (long long)gridDim.x - M;
    long long i = (long long)(blockIdx.x - M) * 256 + tid;
    const long long stride = nblk * 256;
    for (; i < nw16; i += stride) {
      const int4* p = (const int4*)(wsrc + i * 16);
      uint32_t o[4];
#pragma unroll
      for (int k = 0; k < 4; ++k) {
        int4 v = p[k];
        o[k] = (uint32_t)(v.x & 0xff) | ((uint32_t)(v.y & 0xff) << 8) |
               ((uint32_t)(v.z & 0xff) << 16) | ((uint32_t)(v.w & 0xff) << 24);
      }
      uint4 pk = {o[0], o[1], o[2], o[3]};
      *(uint4*)(wq + i * 16) = pk;
    }
  }
}

// ---- general per-row quantize (2-pass), any K%4==0 -------------------------
__global__ __launch_bounds__(256) void qrow(const float* __restrict__ x,
                                            char* __restrict__ q,
                                            float* __restrict__ rs, int K) {
  const int r = blockIdx.x;
  const float* xr = x + (size_t)r * K;
  const int tid = threadIdx.x;
  const int n4 = K >> 2;
  float mx = 0.f;
  for (int i = tid; i < n4; i += 256) {
    float4 v = ((const float4*)xr)[i];
    mx = fmaxf(mx, fmaxf(fmaxf(fabsf(v.x), fabsf(v.y)),
                         fmaxf(fabsf(v.z), fabsf(v.w))));
  }
#pragma unroll
  for (int off = 32; off; off >>= 1) mx = fmaxf(mx, __shfl_down(mx, off));
  __shared__ float smx[4];
  __shared__ float sinv;
  if ((tid & 63) == 0) smx[tid >> 6] = mx;
  __syncthreads();
  if (tid == 0) {
    float m = fmaxf(fmaxf(smx[0], smx[1]), fmaxf(smx[2], smx[3]));
    rs[r] = m / 127.0f;
    sinv = (m > 0.f) ? 127.0f / m : 0.f;
  }
  __syncthreads();
  const float inv = sinv;
  uint32_t* qr = (uint32_t*)(q + (size_t)r * K);
  for (int i = tid; i < n4; i += 256) {
    float4 v = ((const float4*)xr)[i];
    int a0 = (int)rintf(v.x * inv), a1 = (int)rintf(v.y * inv);
    int a2 = (int)rintf(v.z * inv), a3 = (int)rintf(v.w * inv);
    qr[i] = (uint32_t)(a0 & 0xff) | ((uint32_t)(a1 & 0xff) << 8) |
            ((uint32_t)(a2 & 0xff) << 16) | ((uint32_t)(a3 & 0xff) << 24);
  }
}

// ---- w pack (general path) -------------------------------------------------
__global__ void qw_pack(const int* __restrict__ wq, char* __restrict__ q,
                        long long n16) {
  long long i = (long long)blockIdx.x * blockDim.x + threadIdx.x;
  const long long stride = (long long)gridDim.x * blockDim.x;
  for (; i < n16; i += stride) {
    const int4* p = (const int4*)(wq + i * 16);
    uint32_t o[4];
#pragma unroll
    for (int k = 0; k < 4; ++k) {
      int4 v = p[k];
      o[k] = (uint32_t)(v.x & 0xff) | ((uint32_t)(v.y & 0xff) << 8) |
             ((uint32_t)(v.z & 0xff) << 16) | ((uint32_t)(v.w & 0xff) << 24);
    }
    uint4 pk = {o[0], o[1], o[2], o[3]};
    *(uint4*)(q + i * 16) = pk;
  }
}

// ---------------- fallback (no workspace needed, any shape) -----------------
#define FBM 128
#define FBN 128
#define FBK 32

__global__ __launch_bounds__(256) void gemm_fb(
    const float* __restrict__ A, const int* __restrict__ B,
    const float* __restrict__ scaler, float* __restrict__ C,
    int M, int N, int K) {
  __shared__ alignas(16) short As[FBM * FBK];
  __shared__ alignas(16) short Bs[FBN * FBK];

  const int tid = threadIdx.x;
  const int lane = tid & 63;
  const int wid = tid >> 6;
  const int wr = wid >> 1, wc = wid & 1;

  const int nwg = gridDim.x;
  const int ntn = N / FBN;
  int bid = blockIdx.x;
  int q = nwg / NXCD, r = nwg % NXCD;
  int xcd = bid % NXCD, idx = bid / NXCD;
  int swz = (xcd < r ? xcd * (q + 1) : r * (q + 1) + (xcd - r) * q) + idx;
  const int mt = swz / ntn, nt = swz % ntn;
  const int m0 = mt * FBM, n0 = nt * FBN;

  f32x4 acc[4][4] = {};
  const int kiters = K / FBK;

  for (int kt = 0; kt < kiters; ++kt) {
    const int k0 = kt * FBK;
    __syncthreads();
#pragma unroll
    for (int qq = 0; qq < 4; ++qq) {
      int chunk = qq * 256 + tid;
      int row = chunk >> 3;
      int c4 = (chunk & 7) * 4;
      float4 va = *(const float4*)&A[(size_t)(m0 + row) * K + k0 + c4];
      int4 vb = *(const int4*)&B[(size_t)(n0 + row) * K + k0 + c4];
      short4v wa, wb;
      wa[0] = bf16_bits(va.x); wa[1] = bf16_bits(va.y);
      wa[2] = bf16_bits(va.z); wa[3] = bf16_bits(va.w);
      wb[0] = bf16_bits((float)vb.x); wb[1] = bf16_bits((float)vb.y);
      wb[2] = bf16_bits((float)vb.z); wb[3] = bf16_bits((float)vb.w);
      *(short4v*)&As[row * FBK + c4] = wa;
      *(short4v*)&Bs[row * FBK + c4] = wb;
    }
    __syncthreads();
    const int ar = wr * 64 + (lane & 15);
    const int br = wc * 64 + (lane & 15);
    const int ko = (lane >> 4) * 8;
    typedef __attribute__((ext_vector_type(8))) short short8v;
    short8v av[4], bv[4];
#pragma unroll
    for (int i = 0; i < 4; ++i) {
      av[i] = *(const short8v*)&As[(ar + i * 16) * FBK + ko];
      bv[i] = *(const short8v*)&Bs[(br + i * 16) * FBK + ko];
    }
#pragma unroll
    for (int mi = 0; mi < 4; ++mi)
#pragma unroll
      for (int ni = 0; ni < 4; ++ni)
        acc[mi][ni] = __builtin_amdgcn_mfma_f32_16x16x32_bf16(
            av[mi], bv[ni], acc[mi][ni], 0, 0, 0);
  }

  float sc[4];
  const int cc0 = n0 + wc * 64 + (lane & 15);
#pragma unroll
  for (int ni = 0; ni < 4; ++ni) sc[ni] = scaler[cc0 + ni * 16];
  const int cr0 = m0 + wr * 64 + ((lane >> 4) << 2);
#pragma unroll
  for (int mi = 0; mi < 4; ++mi)
#pragma unroll
    for (int j = 0; j < 4; ++j) {
      float* crow = C + (size_t)(cr0 + mi * 16 + j) * N;
#pragma unroll
      for (int ni = 0; ni < 4; ++ni)
        crow[cc0 + ni * 16] = acc[mi][ni][j] * sc[ni];
    }
}

extern "C" void kernel_launch(void* const* d_in, const int* in_sizes, int n_in,
                              void* d_out, int out_size, void* d_ws,
                              size_t ws_size, hipStream_t stream) {
  const float* x = (const float*)d_in[0];       // [M][K] fp32
  const int* w = (const int*)d_in[1];           // [N][K] int32 (0..126)
  const float* sc = (const float*)d_in[2];      // [N] fp32
  float* out = (float*)d_out;                   // [M][N] fp32

  const long long xn = in_sizes[0];             // M*K
  const long long wn = in_sizes[1];             // N*K
  const int N = in_sizes[2];
  const int K = (int)(wn / N);
  const int M = (int)(xn / K);

  const size_t need = (size_t)xn + (size_t)wn + (size_t)M * 4;
  const bool okt = (M % 256 == 0) && (N % 256 == 0) && (K % 128 == 0) &&
                   (K >= 384) && (K % 4 == 0);

  if (ws_size >= need && okt) {
    char* xq = (char*)d_ws;                     // i8 x  [M][K]
    char* wq = xq + xn;                         // i8 w  [N][K]
    float* rs = (float*)(wq + wn);              // row scales [M]
    if (K == 4096) {
      prep4k<<<M + 2048, 256, 0, stream>>>(x, w, xq, wq, rs, M, wn / 16);
    } else {
      qrow<<<M, 256, 0, stream>>>(x, xq, rs, K);
      qw_pack<<<2048, 256, 0, stream>>>(w, wq, wn / 16);
    }
    const int grid = (M / 256) * (N / 256);
    gemm256i8<<<grid, 512, 0, stream>>>(xq, wq, rs, sc, out, M, N, K);
  } else {
    const int grid = (M / FBM) * (N / FBN);
    gemm_fb<<<grid, 256, 0, stream>>>(x, w, sc, out, M, N, K);
  }
}